// Round 1
// baseline (1081.854 us; speedup 1.0000x reference)
//
#include <hip/hip_runtime.h>

// Problem constants
#define EPS 1e-5f
#define B_ 4
#define N_ 8192
#define D_ 1024
#define H_ 8
#define HD_ 128
#define M_TOT 32768   // B*N
#define NQKV 3072     // 3*D

typedef __bf16 bf16x8 __attribute__((ext_vector_type(8)));
typedef float f32x4 __attribute__((ext_vector_type(4)));

__device__ __forceinline__ float bf2f(unsigned short u) {
    unsigned int v = ((unsigned int)u) << 16;
    return __uint_as_float(v);
}
__device__ __forceinline__ unsigned short f2bf(float f) {
    unsigned int u = __float_as_uint(f);
    u += 0x7fffu + ((u >> 16) & 1u);   // RNE
    return (unsigned short)(u >> 16);
}

// async global->LDS, 16B per lane; LDS dest is wave-uniform base + lane*16
__device__ __forceinline__ void gl_lds16(const void* g, void* l) {
    __builtin_amdgcn_global_load_lds(
        (const __attribute__((address_space(1))) unsigned int*)g,
        (__attribute__((address_space(3))) unsigned int*)l, 16, 0, 0);
}

// ---------------- Kernel 1: LayerNorm -> bf16 xn [32768][1024] ----------------
__global__ __launch_bounds__(256) void ln_kernel(const float* __restrict__ x,
                                                 const float* __restrict__ gamma,
                                                 const float* __restrict__ beta,
                                                 unsigned short* __restrict__ xn) {
    const int row = blockIdx.x;
    const int t = threadIdx.x;
    const float* xr = x + (size_t)row * D_;
    float4 xv = ((const float4*)xr)[t];                       // 4 elems/thread
    float s = xv.x + xv.y + xv.z + xv.w;
    float s2 = xv.x * xv.x + xv.y * xv.y + xv.z * xv.z + xv.w * xv.w;
    for (int off = 32; off > 0; off >>= 1) {
        s += __shfl_down(s, off);
        s2 += __shfl_down(s2, off);
    }
    __shared__ float red[8];
    if ((t & 63) == 0) { red[t >> 6] = s; red[4 + (t >> 6)] = s2; }
    __syncthreads();
    float ts = red[0] + red[1] + red[2] + red[3];
    float ts2 = red[4] + red[5] + red[6] + red[7];
    float mu = ts * (1.0f / D_);
    float var = ts2 * (1.0f / D_) - mu * mu;
    float rs = rsqrtf(var + EPS);
    float4 g = ((const float4*)gamma)[t];
    float4 bt = ((const float4*)beta)[t];
    ushort4 o;
    o.x = f2bf((xv.x - mu) * rs * g.x + bt.x);
    o.y = f2bf((xv.y - mu) * rs * g.y + bt.y);
    o.z = f2bf((xv.z - mu) * rs * g.z + bt.z);
    o.w = f2bf((xv.w - mu) * rs * g.w + bt.w);
    ((ushort4*)(xn + (size_t)row * D_))[t] = o;
}

// ---------------- Kernel 2: transpose+cast w [1024][3072] -> wT bf16 [3072][1024]
__global__ __launch_bounds__(256) void wt_kernel(const float* __restrict__ w,
                                                 unsigned short* __restrict__ wT) {
    __shared__ float tile[64][65];
    const int n0 = blockIdx.x * 64;   // 48 blocks
    const int k0 = blockIdx.y * 64;   // 16 blocks
    const int t = threadIdx.x;
    const int tx = t & 63, ty = t >> 6;
    #pragma unroll
    for (int i = 0; i < 16; i++) {
        int r = i * 4 + ty;
        tile[r][tx] = w[(size_t)(k0 + r) * NQKV + n0 + tx];
    }
    __syncthreads();
    #pragma unroll
    for (int i = 0; i < 16; i++) {
        int r = i * 4 + ty;
        wT[(size_t)(n0 + r) * D_ + k0 + tx] = f2bf(tile[tx][r]);
    }
}

// ---------------- Kernel 3: fused QKV GEMM (bf16 MFMA) + activations ----------
// C[32768][3072] tiled 128x128, BK=32, 4 waves each doing 4x4 tiles of 16x16x32.
__global__ __launch_bounds__(256) void qkv_gemm(const unsigned short* __restrict__ xn,
                                                const unsigned short* __restrict__ wT,
                                                const int* __restrict__ mask,
                                                unsigned short* __restrict__ qws,
                                                unsigned short* __restrict__ kws,
                                                unsigned short* __restrict__ vws) {
    __shared__ unsigned short As[128 * 32];   // [m][k] 8KB
    __shared__ unsigned short Bs[128 * 32];   // [n][k] 8KB
    const int t = threadIdx.x;
    const int w = t >> 6, l = t & 63;
    const int quad = l >> 4, ln16 = l & 15;
    const int m0 = blockIdx.y * 128;
    const int n0 = blockIdx.x * 128;
    const int wm = (w >> 1) * 64, wn = (w & 1) * 64;

    f32x4 acc[4][4] = {};

    // staging: LDS byte o = issue*4096 + w*1024 + lane*16 -> m = issue*64 + w*16 + l/4, k = (l&3)*8
    const unsigned short* aG = xn + (size_t)(m0 + w * 16 + (l >> 2)) * D_ + (l & 3) * 8;
    const unsigned short* bG = wT + (size_t)(n0 + w * 16 + (l >> 2)) * D_ + (l & 3) * 8;
    char* AsB = (char*)As;
    char* BsB = (char*)Bs;
    char* aL0 = AsB + w * 1024;
    char* aL1 = AsB + 4096 + w * 1024;
    char* bL0 = BsB + w * 1024;
    char* bL1 = BsB + 4096 + w * 1024;

    for (int k0 = 0; k0 < 1024; k0 += 32) {
        gl_lds16(aG + k0, aL0);
        gl_lds16(aG + 64 * 1024 + k0, aL1);
        gl_lds16(bG + k0, bL0);
        gl_lds16(bG + 64 * 1024 + k0, bL1);
        __syncthreads();   // drains vmcnt for global_load_lds
        bf16x8 af[4], bfr[4];
        #pragma unroll
        for (int mi = 0; mi < 4; mi++)
            af[mi] = *(const bf16x8*)(AsB + (wm + mi * 16 + ln16) * 64 + quad * 16);
        #pragma unroll
        for (int ni = 0; ni < 4; ni++)
            bfr[ni] = *(const bf16x8*)(BsB + (wn + ni * 16 + ln16) * 64 + quad * 16);
        #pragma unroll
        for (int mi = 0; mi < 4; mi++)
            #pragma unroll
            for (int ni = 0; ni < 4; ni++)
                acc[mi][ni] = __builtin_amdgcn_mfma_f32_16x16x32_bf16(af[mi], bfr[ni],
                                                                      acc[mi][ni], 0, 0, 0);
        __syncthreads();
    }

    // epilogue: region 0=q (sigmoid), 1=k (tanh+mask), 2=v (identity)
    const int region = n0 >> 10;
    const int cbase = n0 & 1023;
    unsigned short* dst = (region == 0) ? qws : (region == 1) ? kws : vws;
    #pragma unroll
    for (int mi = 0; mi < 4; mi++) {
        #pragma unroll
        for (int r = 0; r < 4; r++) {
            int gm = m0 + wm + mi * 16 + quad * 4 + r;   // C/D row = quad*4+reg
            int mk = (region == 1) ? mask[gm] : 0;
            #pragma unroll
            for (int ni = 0; ni < 4; ni++) {
                int cc = cbase + wn + ni * 16 + ln16;    // C/D col = lane&15
                float v = acc[mi][ni][r];
                if (region == 0) v = 1.0f / (1.0f + expf(-v));
                else if (region == 1) v = mk ? 0.0f : tanhf(v);
                dst[(size_t)gm * D_ + cc] = f2bf(v);
            }
        }
    }
}

// ---------------- Kernel 4: kv[bh][d][e] = sum_n k[n][d]*v[n][e] --------------
// grid (32 chunks, 32 bh); per-block partial over 256 rows, atomicAdd to fp32 kv.
__global__ __launch_bounds__(256) void kv_kernel(const unsigned short* __restrict__ kws,
                                                 const unsigned short* __restrict__ vws,
                                                 float* __restrict__ kv) {
    const int bh = blockIdx.y;
    const int b = bh >> 3, h = bh & 7;
    const int chunk = blockIdx.x;
    const int t = threadIdx.x;
    const int ti = t >> 4, tj = t & 15;
    __shared__ float kf[4][128];
    __shared__ float vf[4][128];
    float acc[8][8] = {};
    size_t rowbase = (size_t)b * N_ + (size_t)chunk * 256;
    const unsigned short* kp = kws + rowbase * D_ + h * HD_;
    const unsigned short* vp = vws + rowbase * D_ + h * HD_;
    const int rr = t >> 6, c2 = (t & 63) * 2;
    for (int n = 0; n < 256; n += 4) {
        __syncthreads();
        unsigned int ku = *(const unsigned int*)(kp + (size_t)(n + rr) * D_ + c2);
        unsigned int vu = *(const unsigned int*)(vp + (size_t)(n + rr) * D_ + c2);
        kf[rr][c2]     = bf2f((unsigned short)(ku & 0xffff));
        kf[rr][c2 + 1] = bf2f((unsigned short)(ku >> 16));
        vf[rr][c2]     = bf2f((unsigned short)(vu & 0xffff));
        vf[rr][c2 + 1] = bf2f((unsigned short)(vu >> 16));
        __syncthreads();
        #pragma unroll
        for (int nn = 0; nn < 4; nn++) {
            float kr[8], vr[8];
            *(float4*)(kr)     = *(const float4*)&kf[nn][ti * 8];
            *(float4*)(kr + 4) = *(const float4*)&kf[nn][ti * 8 + 4];
            *(float4*)(vr)     = *(const float4*)&vf[nn][tj * 8];
            *(float4*)(vr + 4) = *(const float4*)&vf[nn][tj * 8 + 4];
            #pragma unroll
            for (int i = 0; i < 8; i++)
                #pragma unroll
                for (int j = 0; j < 8; j++)
                    acc[i][j] += kr[i] * vr[j];
        }
    }
    float* dst = kv + (size_t)bh * (HD_ * HD_);
    #pragma unroll
    for (int i = 0; i < 8; i++)
        #pragma unroll
        for (int j = 0; j < 8; j++)
            atomicAdd(&dst[(ti * 8 + i) * HD_ + tj * 8 + j], acc[i][j]);
}

// ---------------- Kernel 5: out[n][e] = sum_d q[n][d]*kv[d][e] ----------------
// grid (128 ntiles of 64 rows, 32 bh)
__global__ __launch_bounds__(256) void out_kernel(const unsigned short* __restrict__ qws,
                                                  const float* __restrict__ kv,
                                                  float* __restrict__ out) {
    const int bh = blockIdx.y, b = bh >> 3, h = bh & 7;
    const int n0 = blockIdx.x * 64;
    const int t = threadIdx.x;
    const int rg = t >> 4, cg = t & 15;   // 4 rows x 8 cols per thread
    __shared__ float kvs[32][128];
    __shared__ float qs[64][32];
    float acc[4][8] = {};
    const float* kvp = kv + (size_t)bh * (HD_ * HD_);
    const unsigned short* qp = qws + ((size_t)b * N_ + n0) * D_ + h * HD_;
    for (int i0 = 0; i0 < 128; i0 += 32) {
        __syncthreads();
        #pragma unroll
        for (int rep = 0; rep < 4; rep++) {
            int r = rep * 8 + (t >> 5), c = (t & 31) * 4;
            *(float4*)&kvs[r][c] = *(const float4*)(kvp + (size_t)(i0 + r) * HD_ + c);
        }
        {
            int r = t >> 2, p = (t & 3) * 8;
            const unsigned short* qrow = qp + (size_t)r * D_ + i0 + p;
            uint4 u = *(const uint4*)qrow;
            float* q8 = &qs[r][p];
            q8[0] = bf2f((unsigned short)(u.x & 0xffff));
            q8[1] = bf2f((unsigned short)(u.x >> 16));
            q8[2] = bf2f((unsigned short)(u.y & 0xffff));
            q8[3] = bf2f((unsigned short)(u.y >> 16));
            q8[4] = bf2f((unsigned short)(u.z & 0xffff));
            q8[5] = bf2f((unsigned short)(u.z >> 16));
            q8[6] = bf2f((unsigned short)(u.w & 0xffff));
            q8[7] = bf2f((unsigned short)(u.w >> 16));
        }
        __syncthreads();
        #pragma unroll
        for (int ii = 0; ii < 32; ii++) {
            float qv[4];
            #pragma unroll
            for (int r2 = 0; r2 < 4; r2++) qv[r2] = qs[rg * 4 + r2][ii];
            float kvr[8];
            *(float4*)kvr       = *(const float4*)&kvs[ii][cg * 8];
            *(float4*)(kvr + 4) = *(const float4*)&kvs[ii][cg * 8 + 4];
            #pragma unroll
            for (int r2 = 0; r2 < 4; r2++)
                #pragma unroll
                for (int cc = 0; cc < 8; cc++)
                    acc[r2][cc] += qv[r2] * kvr[cc];
        }
    }
    #pragma unroll
    for (int r2 = 0; r2 < 4; r2++) {
        float* orow = out + ((size_t)b * N_ + n0 + rg * 4 + r2) * D_ + h * HD_ + cg * 8;
        float4 v0 = {acc[r2][0], acc[r2][1], acc[r2][2], acc[r2][3]};
        float4 v1 = {acc[r2][4], acc[r2][5], acc[r2][6], acc[r2][7]};
        ((float4*)orow)[0] = v0;
        ((float4*)orow)[1] = v1;
    }
}

// ---------------- launch ----------------
extern "C" void kernel_launch(void* const* d_in, const int* in_sizes, int n_in,
                              void* d_out, int out_size, void* d_ws, size_t ws_size,
                              hipStream_t stream) {
    const float* x     = (const float*)d_in[0];
    const int*   mask  = (const int*)d_in[1];
    const float* w     = (const float*)d_in[2];
    const float* gamma = (const float*)d_in[3];
    const float* beta  = (const float*)d_in[4];
    float* out = (float*)d_out;
    char* ws = (char*)d_ws;

    // workspace layout (total ~264 MB)
    unsigned short* xn  = (unsigned short*)(ws + 0);              // 64 MB
    unsigned short* wT  = (unsigned short*)(ws + 67108864ull);    // 6 MB
    unsigned short* qws = (unsigned short*)(ws + 73400320ull);    // 64 MB
    unsigned short* kws = (unsigned short*)(ws + 140509184ull);   // 64 MB
    unsigned short* vws = (unsigned short*)(ws + 207618048ull);   // 64 MB
    float* kv           = (float*)(ws + 274726912ull);            // 2 MB

    hipMemsetAsync(kv, 0, 32 * HD_ * HD_ * sizeof(float), stream);
    hipLaunchKernelGGL(ln_kernel, dim3(M_TOT), dim3(256), 0, stream, x, gamma, beta, xn);
    hipLaunchKernelGGL(wt_kernel, dim3(48, 16), dim3(256), 0, stream, w, wT);
    hipLaunchKernelGGL(qkv_gemm, dim3(NQKV / 128, M_TOT / 128), dim3(256), 0, stream,
                       xn, wT, mask, qws, kws, vws);
    hipLaunchKernelGGL(kv_kernel, dim3(32, 32), dim3(256), 0, stream, kws, vws, kv);
    hipLaunchKernelGGL(out_kernel, dim3(N_ / 64, 32), dim3(256), 0, stream, qws, kv, out);
}

// Round 2
// 739.981 us; speedup vs baseline: 1.4620x; 1.4620x over previous
//
#include <hip/hip_runtime.h>

// Problem constants
#define EPS 1e-5f
#define B_ 4
#define N_ 8192
#define D_ 1024
#define H_ 8
#define HD_ 128
#define M_TOT 32768   // B*N
#define NQKV 3072     // 3*D

typedef __bf16 bf16x8 __attribute__((ext_vector_type(8)));
typedef float f32x4 __attribute__((ext_vector_type(4)));

__device__ __forceinline__ float bf2f(unsigned short u) {
    unsigned int v = ((unsigned int)u) << 16;
    return __uint_as_float(v);
}
__device__ __forceinline__ unsigned short f2bf(float f) {
    unsigned int u = __float_as_uint(f);
    u += 0x7fffu + ((u >> 16) & 1u);   // RNE
    return (unsigned short)(u >> 16);
}

// async global->LDS, 16B per lane; LDS dest is wave-uniform base + lane*16
__device__ __forceinline__ void gl_lds16(const void* g, void* l) {
    __builtin_amdgcn_global_load_lds(
        (const __attribute__((address_space(1))) unsigned int*)g,
        (__attribute__((address_space(3))) unsigned int*)l, 16, 0, 0);
}

// ---------------- Kernel 1: LayerNorm -> bf16 xn [32768][1024] ----------------
__global__ __launch_bounds__(256) void ln_kernel(const float* __restrict__ x,
                                                 const float* __restrict__ gamma,
                                                 const float* __restrict__ beta,
                                                 unsigned short* __restrict__ xn) {
    const int row = blockIdx.x;
    const int t = threadIdx.x;
    const float* xr = x + (size_t)row * D_;
    float4 xv = ((const float4*)xr)[t];                       // 4 elems/thread
    float s = xv.x + xv.y + xv.z + xv.w;
    float s2 = xv.x * xv.x + xv.y * xv.y + xv.z * xv.z + xv.w * xv.w;
    for (int off = 32; off > 0; off >>= 1) {
        s += __shfl_down(s, off);
        s2 += __shfl_down(s2, off);
    }
    __shared__ float red[8];
    if ((t & 63) == 0) { red[t >> 6] = s; red[4 + (t >> 6)] = s2; }
    __syncthreads();
    float ts = red[0] + red[1] + red[2] + red[3];
    float ts2 = red[4] + red[5] + red[6] + red[7];
    float mu = ts * (1.0f / D_);
    float var = ts2 * (1.0f / D_) - mu * mu;
    float rs = rsqrtf(var + EPS);
    float4 g = ((const float4*)gamma)[t];
    float4 bt = ((const float4*)beta)[t];
    ushort4 o;
    o.x = f2bf((xv.x - mu) * rs * g.x + bt.x);
    o.y = f2bf((xv.y - mu) * rs * g.y + bt.y);
    o.z = f2bf((xv.z - mu) * rs * g.z + bt.z);
    o.w = f2bf((xv.w - mu) * rs * g.w + bt.w);
    ((ushort4*)(xn + (size_t)row * D_))[t] = o;
}

// ---------------- Kernel 2: transpose+cast w [1024][3072] -> wT bf16 [3072][1024]
__global__ __launch_bounds__(256) void wt_kernel(const float* __restrict__ w,
                                                 unsigned short* __restrict__ wT) {
    __shared__ float tile[64][65];
    const int n0 = blockIdx.x * 64;   // 48 blocks
    const int k0 = blockIdx.y * 64;   // 16 blocks
    const int t = threadIdx.x;
    const int tx = t & 63, ty = t >> 6;
    #pragma unroll
    for (int i = 0; i < 16; i++) {
        int r = i * 4 + ty;
        tile[r][tx] = w[(size_t)(k0 + r) * NQKV + n0 + tx];
    }
    __syncthreads();
    #pragma unroll
    for (int i = 0; i < 16; i++) {
        int r = i * 4 + ty;
        wT[(size_t)(n0 + r) * D_ + k0 + tx] = f2bf(tile[tx][r]);
    }
}

// ---------------- Kernel 3: fused QKV GEMM (bf16 MFMA) + activations ----------
// C[32768][3072] tiled 128x128, BK=32, 4 waves each doing 4x4 tiles of 16x16x32.
// q written token-major [32768][1024]; k,v written FEATURE-major (transposed)
// kT/vT[bh][128 feat][8192 tok] via LDS transpose (stride-136 rows, 16B aligned).
#define CT_STRIDE 136
__global__ __launch_bounds__(256) void qkv_gemm(const unsigned short* __restrict__ xn,
                                                const unsigned short* __restrict__ wT,
                                                const int* __restrict__ mask,
                                                unsigned short* __restrict__ qws,
                                                unsigned short* __restrict__ kT,
                                                unsigned short* __restrict__ vT) {
    __shared__ unsigned short ShB[128 * CT_STRIDE];   // 34816 B; mainloop uses first 16 KB
    unsigned short* As = ShB;          // [128 m][32 k]
    unsigned short* Bs = ShB + 4096;   // [128 n][32 k]
    const int t = threadIdx.x;
    const int w = t >> 6, l = t & 63;
    const int quad = l >> 4, ln16 = l & 15;
    const int m0 = blockIdx.y * 128;
    const int n0 = blockIdx.x * 128;
    const int wm = (w >> 1) * 64, wn = (w & 1) * 64;

    f32x4 acc[4][4] = {};

    const unsigned short* aG = xn + (size_t)(m0 + w * 16 + (l >> 2)) * D_ + (l & 3) * 8;
    const unsigned short* bG = wT + (size_t)(n0 + w * 16 + (l >> 2)) * D_ + (l & 3) * 8;
    char* AsB = (char*)As;
    char* BsB = (char*)Bs;
    char* aL0 = AsB + w * 1024;
    char* aL1 = AsB + 4096 + w * 1024;
    char* bL0 = BsB + w * 1024;
    char* bL1 = BsB + 4096 + w * 1024;

    for (int k0 = 0; k0 < 1024; k0 += 32) {
        gl_lds16(aG + k0, aL0);
        gl_lds16(aG + 64 * 1024 + k0, aL1);
        gl_lds16(bG + k0, bL0);
        gl_lds16(bG + 64 * 1024 + k0, bL1);
        __syncthreads();   // drains vmcnt for global_load_lds
        bf16x8 af[4], bfr[4];
        #pragma unroll
        for (int mi = 0; mi < 4; mi++)
            af[mi] = *(const bf16x8*)(AsB + (wm + mi * 16 + ln16) * 64 + quad * 16);
        #pragma unroll
        for (int ni = 0; ni < 4; ni++)
            bfr[ni] = *(const bf16x8*)(BsB + (wn + ni * 16 + ln16) * 64 + quad * 16);
        #pragma unroll
        for (int mi = 0; mi < 4; mi++)
            #pragma unroll
            for (int ni = 0; ni < 4; ni++)
                acc[mi][ni] = __builtin_amdgcn_mfma_f32_16x16x32_bf16(af[mi], bfr[ni],
                                                                      acc[mi][ni], 0, 0, 0);
        __syncthreads();
    }

    // epilogue: region 0=q (sigmoid, token-major), 1=k (tanh+mask, transposed),
    //           2=v (identity, transposed)
    const int region = n0 >> 10;
    const int cbase = n0 & 1023;
    if (region == 0) {
        #pragma unroll
        for (int mi = 0; mi < 4; mi++) {
            #pragma unroll
            for (int r = 0; r < 4; r++) {
                int gm = m0 + wm + mi * 16 + quad * 4 + r;   // C/D row = quad*4+reg
                #pragma unroll
                for (int ni = 0; ni < 4; ni++) {
                    int cc = cbase + wn + ni * 16 + ln16;    // C/D col = lane&15
                    float v = acc[mi][ni][r];
                    v = 1.0f / (1.0f + expf(-v));
                    qws[(size_t)gm * D_ + cc] = f2bf(v);
                }
            }
        }
    } else {
        // phase 1: store tile into LDS transposed [feat][tok], packed 4 toks/write
        #pragma unroll
        for (int mi = 0; mi < 4; mi++) {
            int tok0 = wm + mi * 16 + quad * 4;
            int mk0 = 0, mk1 = 0, mk2 = 0, mk3 = 0;
            if (region == 1) {
                mk0 = mask[m0 + tok0];
                mk1 = mask[m0 + tok0 + 1];
                mk2 = mask[m0 + tok0 + 2];
                mk3 = mask[m0 + tok0 + 3];
            }
            #pragma unroll
            for (int ni = 0; ni < 4; ni++) {
                int fl = wn + ni * 16 + ln16;
                float v0 = acc[mi][ni][0], v1 = acc[mi][ni][1];
                float v2 = acc[mi][ni][2], v3 = acc[mi][ni][3];
                if (region == 1) {
                    v0 = mk0 ? 0.0f : tanhf(v0);
                    v1 = mk1 ? 0.0f : tanhf(v1);
                    v2 = mk2 ? 0.0f : tanhf(v2);
                    v3 = mk3 ? 0.0f : tanhf(v3);
                }
                ushort4 pk;
                pk.x = f2bf(v0); pk.y = f2bf(v1); pk.z = f2bf(v2); pk.w = f2bf(v3);
                *(ushort4*)&ShB[fl * CT_STRIDE + tok0] = pk;   // 8B-aligned ds_write_b64
            }
        }
        __syncthreads();
        // phase 2: coalesced transposed global write (256B per feature row)
        unsigned short* dstT = (region == 1) ? kT : vT;
        const int h = cbase >> 7;          // block covers exactly one head
        const int b = m0 >> 13;
        const int ntok0 = m0 & 8191;
        #pragma unroll
        for (int p = 0; p < 8; p++) {
            int fl = p * 16 + (t >> 4);
            int tok = (t & 15) * 8;
            uint4 u = *(const uint4*)&ShB[fl * CT_STRIDE + tok];   // 16B-aligned b128
            *(uint4*)(dstT + ((size_t)(b * 8 + h) * 128 + fl) * 8192 + ntok0 + tok) = u;
        }
    }
}

// ---------------- Kernel 4: kv[bh][d][e] = sum_n kT[d][n]*vT[e][n] (MFMA) -----
// gemm_bt: A = kT (m=d), B^T = vT (n=e). grid (16 K-chunks, 32 bh), tile 128x128,
// BK=32, K-chunk 512. Epilogue: quad-coalesced atomicAdd into fp32 kv.
__global__ __launch_bounds__(256) void kv_mfma(const unsigned short* __restrict__ kT,
                                               const unsigned short* __restrict__ vT,
                                               float* __restrict__ kv) {
    __shared__ unsigned short As[128 * 32];   // kT rows (d)
    __shared__ unsigned short Bs[128 * 32];   // vT rows (e)
    const int t = threadIdx.x;
    const int w = t >> 6, l = t & 63;
    const int quad = l >> 4, ln16 = l & 15;
    const int bh = blockIdx.y;
    const int kc0 = blockIdx.x * 512;
    const int wm = (w >> 1) * 64, wn = (w & 1) * 64;

    f32x4 acc[4][4] = {};

    const size_t base = (size_t)bh * 128 * 8192;
    const unsigned short* aG = kT + base + (size_t)(w * 16 + (l >> 2)) * 8192
                               + (l & 3) * 8 + kc0;
    const unsigned short* bG = vT + base + (size_t)(w * 16 + (l >> 2)) * 8192
                               + (l & 3) * 8 + kc0;
    char* AsB = (char*)As;
    char* BsB = (char*)Bs;
    char* aL0 = AsB + w * 1024;
    char* aL1 = AsB + 4096 + w * 1024;
    char* bL0 = BsB + w * 1024;
    char* bL1 = BsB + 4096 + w * 1024;

    for (int kk = 0; kk < 512; kk += 32) {
        gl_lds16(aG + kk, aL0);
        gl_lds16(aG + 64 * 8192 + kk, aL1);
        gl_lds16(bG + kk, bL0);
        gl_lds16(bG + 64 * 8192 + kk, bL1);
        __syncthreads();
        bf16x8 af[4], bfr[4];
        #pragma unroll
        for (int mi = 0; mi < 4; mi++)
            af[mi] = *(const bf16x8*)(AsB + (wm + mi * 16 + ln16) * 64 + quad * 16);
        #pragma unroll
        for (int ni = 0; ni < 4; ni++)
            bfr[ni] = *(const bf16x8*)(BsB + (wn + ni * 16 + ln16) * 64 + quad * 16);
        #pragma unroll
        for (int mi = 0; mi < 4; mi++)
            #pragma unroll
            for (int ni = 0; ni < 4; ni++)
                acc[mi][ni] = __builtin_amdgcn_mfma_f32_16x16x32_bf16(af[mi], bfr[ni],
                                                                      acc[mi][ni], 0, 0, 0);
        __syncthreads();
    }

    float* dst = kv + (size_t)bh * (HD_ * HD_);
    #pragma unroll
    for (int mi = 0; mi < 4; mi++) {
        #pragma unroll
        for (int r = 0; r < 4; r++) {
            int d = wm + mi * 16 + quad * 4 + r;   // C/D row
            #pragma unroll
            for (int ni = 0; ni < 4; ni++) {
                int e = wn + ni * 16 + ln16;       // C/D col (consecutive lanes)
                atomicAdd(&dst[d * HD_ + e], acc[mi][ni][r]);
            }
        }
    }
}

// ---------------- Kernel 5: out[n][e] = sum_d q[n][d]*kv[d][e] ----------------
// grid (128 ntiles of 64 rows, 32 bh)
__global__ __launch_bounds__(256) void out_kernel(const unsigned short* __restrict__ qws,
                                                  const float* __restrict__ kv,
                                                  float* __restrict__ out) {
    const int bh = blockIdx.y, b = bh >> 3, h = bh & 7;
    const int n0 = blockIdx.x * 64;
    const int t = threadIdx.x;
    const int rg = t >> 4, cg = t & 15;   // 4 rows x 8 cols per thread
    __shared__ float kvs[32][128];
    __shared__ float qs[64][32];
    float acc[4][8] = {};
    const float* kvp = kv + (size_t)bh * (HD_ * HD_);
    const unsigned short* qp = qws + ((size_t)b * N_ + n0) * D_ + h * HD_;
    for (int i0 = 0; i0 < 128; i0 += 32) {
        __syncthreads();
        #pragma unroll
        for (int rep = 0; rep < 4; rep++) {
            int r = rep * 8 + (t >> 5), c = (t & 31) * 4;
            *(float4*)&kvs[r][c] = *(const float4*)(kvp + (size_t)(i0 + r) * HD_ + c);
        }
        {
            int r = t >> 2, p = (t & 3) * 8;
            const unsigned short* qrow = qp + (size_t)r * D_ + i0 + p;
            uint4 u = *(const uint4*)qrow;
            float* q8 = &qs[r][p];
            q8[0] = bf2f((unsigned short)(u.x & 0xffff));
            q8[1] = bf2f((unsigned short)(u.x >> 16));
            q8[2] = bf2f((unsigned short)(u.y & 0xffff));
            q8[3] = bf2f((unsigned short)(u.y >> 16));
            q8[4] = bf2f((unsigned short)(u.z & 0xffff));
            q8[5] = bf2f((unsigned short)(u.z >> 16));
            q8[6] = bf2f((unsigned short)(u.w & 0xffff));
            q8[7] = bf2f((unsigned short)(u.w >> 16));
        }
        __syncthreads();
        #pragma unroll
        for (int ii = 0; ii < 32; ii++) {
            float qv[4];
            #pragma unroll
            for (int r2 = 0; r2 < 4; r2++) qv[r2] = qs[rg * 4 + r2][ii];
            float kvr[8];
            *(float4*)kvr       = *(const float4*)&kvs[ii][cg * 8];
            *(float4*)(kvr + 4) = *(const float4*)&kvs[ii][cg * 8 + 4];
            #pragma unroll
            for (int r2 = 0; r2 < 4; r2++)
                #pragma unroll
                for (int cc = 0; cc < 8; cc++)
                    acc[r2][cc] += qv[r2] * kvr[cc];
        }
    }
    #pragma unroll
    for (int r2 = 0; r2 < 4; r2++) {
        float* orow = out + ((size_t)b * N_ + n0 + rg * 4 + r2) * D_ + h * HD_ + cg * 8;
        float4 v0 = {acc[r2][0], acc[r2][1], acc[r2][2], acc[r2][3]};
        float4 v1 = {acc[r2][4], acc[r2][5], acc[r2][6], acc[r2][7]};
        ((float4*)orow)[0] = v0;
        ((float4*)orow)[1] = v1;
    }
}

// ---------------- launch ----------------
extern "C" void kernel_launch(void* const* d_in, const int* in_sizes, int n_in,
                              void* d_out, int out_size, void* d_ws, size_t ws_size,
                              hipStream_t stream) {
    const float* x     = (const float*)d_in[0];
    const int*   mask  = (const int*)d_in[1];
    const float* w     = (const float*)d_in[2];
    const float* gamma = (const float*)d_in[3];
    const float* beta  = (const float*)d_in[4];
    float* out = (float*)d_out;
    char* ws = (char*)d_ws;

    // workspace layout (total ~266 MB)
    unsigned short* xn  = (unsigned short*)(ws + 0);              // 64 MB
    unsigned short* wT  = (unsigned short*)(ws + 67108864ull);    // 6 MB
    unsigned short* qws = (unsigned short*)(ws + 73400320ull);    // 64 MB
    unsigned short* kT  = (unsigned short*)(ws + 140509184ull);   // 64 MB [bh][128][8192]
    unsigned short* vT  = (unsigned short*)(ws + 207618048ull);   // 64 MB [bh][128][8192]
    float* kv           = (float*)(ws + 274726912ull);            // 2 MB

    hipMemsetAsync(kv, 0, 32 * HD_ * HD_ * sizeof(float), stream);
    hipLaunchKernelGGL(ln_kernel, dim3(M_TOT), dim3(256), 0, stream, x, gamma, beta, xn);
    hipLaunchKernelGGL(wt_kernel, dim3(48, 16), dim3(256), 0, stream, w, wT);
    hipLaunchKernelGGL(qkv_gemm, dim3(NQKV / 128, M_TOT / 128), dim3(256), 0, stream,
                       xn, wT, mask, qws, kT, vT);
    hipLaunchKernelGGL(kv_mfma, dim3(16, 32), dim3(256), 0, stream, kT, vT, kv);
    hipLaunchKernelGGL(out_kernel, dim3(N_ / 64, 32), dim3(256), 0, stream, qws, kv, out);
}

// Round 3
// 546.432 us; speedup vs baseline: 1.9799x; 1.3542x over previous
//
#include <hip/hip_runtime.h>

// Problem constants
#define EPS 1e-5f
#define B_ 4
#define N_ 8192
#define D_ 1024
#define H_ 8
#define HD_ 128
#define M_TOT 32768   // B*N
#define NQKV 3072     // 3*D

typedef __bf16 bf16x8 __attribute__((ext_vector_type(8)));
typedef float f32x4 __attribute__((ext_vector_type(4)));

__device__ __forceinline__ float bf2f(unsigned short u) {
    unsigned int v = ((unsigned int)u) << 16;
    return __uint_as_float(v);
}
__device__ __forceinline__ unsigned short f2bf(float f) {
    unsigned int u = __float_as_uint(f);
    u += 0x7fffu + ((u >> 16) & 1u);   // RNE
    return (unsigned short)(u >> 16);
}

// fast activations: v_exp_f32 + v_rcp_f32 (~1e-6 rel err, saturates correctly)
__device__ __forceinline__ float fast_sigmoid(float v) {
    return __builtin_amdgcn_rcpf(1.0f + __expf(-v));
}
__device__ __forceinline__ float fast_tanh(float v) {
    return 1.0f - 2.0f * __builtin_amdgcn_rcpf(1.0f + __expf(2.0f * v));
}

// async global->LDS, 16B per lane; LDS dest is wave-uniform base + lane*16
__device__ __forceinline__ void gl_lds16(const void* g, void* l) {
    __builtin_amdgcn_global_load_lds(
        (const __attribute__((address_space(1))) unsigned int*)g,
        (__attribute__((address_space(3))) unsigned int*)l, 16, 0, 0);
}

// ---------------- Kernel 1: LayerNorm -> bf16 xn [32768][1024] ----------------
__global__ __launch_bounds__(256) void ln_kernel(const float* __restrict__ x,
                                                 const float* __restrict__ gamma,
                                                 const float* __restrict__ beta,
                                                 unsigned short* __restrict__ xn) {
    const int row = blockIdx.x;
    const int t = threadIdx.x;
    const float* xr = x + (size_t)row * D_;
    float4 xv = ((const float4*)xr)[t];                       // 4 elems/thread
    float s = xv.x + xv.y + xv.z + xv.w;
    float s2 = xv.x * xv.x + xv.y * xv.y + xv.z * xv.z + xv.w * xv.w;
    for (int off = 32; off > 0; off >>= 1) {
        s += __shfl_down(s, off);
        s2 += __shfl_down(s2, off);
    }
    __shared__ float red[8];
    if ((t & 63) == 0) { red[t >> 6] = s; red[4 + (t >> 6)] = s2; }
    __syncthreads();
    float ts = red[0] + red[1] + red[2] + red[3];
    float ts2 = red[4] + red[5] + red[6] + red[7];
    float mu = ts * (1.0f / D_);
    float var = ts2 * (1.0f / D_) - mu * mu;
    float rs = rsqrtf(var + EPS);
    float4 g = ((const float4*)gamma)[t];
    float4 bt = ((const float4*)beta)[t];
    ushort4 o;
    o.x = f2bf((xv.x - mu) * rs * g.x + bt.x);
    o.y = f2bf((xv.y - mu) * rs * g.y + bt.y);
    o.z = f2bf((xv.z - mu) * rs * g.z + bt.z);
    o.w = f2bf((xv.w - mu) * rs * g.w + bt.w);
    ((ushort4*)(xn + (size_t)row * D_))[t] = o;
}

// ---------------- Kernel 2: transpose+cast w [1024][3072] -> wT bf16 [3072][1024]
__global__ __launch_bounds__(256) void wt_kernel(const float* __restrict__ w,
                                                 unsigned short* __restrict__ wT) {
    __shared__ float tile[64][65];
    const int n0 = blockIdx.x * 64;   // 48 blocks
    const int k0 = blockIdx.y * 64;   // 16 blocks
    const int t = threadIdx.x;
    const int tx = t & 63, ty = t >> 6;
    #pragma unroll
    for (int i = 0; i < 16; i++) {
        int r = i * 4 + ty;
        tile[r][tx] = w[(size_t)(k0 + r) * NQKV + n0 + tx];
    }
    __syncthreads();
    #pragma unroll
    for (int i = 0; i < 16; i++) {
        int r = i * 4 + ty;
        wT[(size_t)(n0 + r) * D_ + k0 + tx] = f2bf(tile[tx][r]);
    }
}

// ---------------- Kernel 3: fused QKV GEMM (bf16 MFMA) + activations ----------
// C[32768][3072] tiled 128x128, BK=64 (two 32-K stages per barrier pair),
// 4 waves each doing 4x4 tiles of 16x16x32.
// q written token-major [32768][1024]; k,v written FEATURE-major (transposed)
// kT/vT[bh][128 feat][8192 tok] via LDS transpose (stride-136 rows, 16B aligned).
#define CT_STRIDE 136
__global__ __launch_bounds__(256, 3) void qkv_gemm(const unsigned short* __restrict__ xn,
                                                   const unsigned short* __restrict__ wT,
                                                   const int* __restrict__ mask,
                                                   unsigned short* __restrict__ qws,
                                                   unsigned short* __restrict__ kT,
                                                   unsigned short* __restrict__ vT) {
    __shared__ unsigned short ShB[128 * CT_STRIDE];   // 34816 B; mainloop uses 32 KB
    const int t = threadIdx.x;
    const int w = t >> 6, l = t & 63;
    const int quad = l >> 4, ln16 = l & 15;
    const int m0 = blockIdx.y * 128;
    const int n0 = blockIdx.x * 128;
    const int wm = (w >> 1) * 64, wn = (w & 1) * 64;

    f32x4 acc[4][4] = {};

    const unsigned short* aG = xn + (size_t)(m0 + w * 16 + (l >> 2)) * D_ + (l & 3) * 8;
    const unsigned short* bG = wT + (size_t)(n0 + w * 16 + (l >> 2)) * D_ + (l & 3) * 8;
    char* SB = (char*)ShB;
    // staging layout: A stage s at SB + s*8192 (two 4KB halves); B at +16384.

    for (int k0 = 0; k0 < 1024; k0 += 64) {
        #pragma unroll
        for (int s = 0; s < 2; s++) {
            gl_lds16(aG + k0 + s * 32,            SB + s * 8192 + w * 1024);
            gl_lds16(aG + 64 * D_ + k0 + s * 32,  SB + s * 8192 + 4096 + w * 1024);
            gl_lds16(bG + k0 + s * 32,            SB + 16384 + s * 8192 + w * 1024);
            gl_lds16(bG + 64 * D_ + k0 + s * 32,  SB + 16384 + s * 8192 + 4096 + w * 1024);
        }
        __syncthreads();   // drains vmcnt for global_load_lds
        #pragma unroll
        for (int s = 0; s < 2; s++) {
            const char* A0 = SB + s * 8192;
            const char* B0 = SB + 16384 + s * 8192;
            bf16x8 af[4], bfr[4];
            #pragma unroll
            for (int mi = 0; mi < 4; mi++)
                af[mi] = *(const bf16x8*)(A0 + (wm + mi * 16 + ln16) * 64 + quad * 16);
            #pragma unroll
            for (int ni = 0; ni < 4; ni++)
                bfr[ni] = *(const bf16x8*)(B0 + (wn + ni * 16 + ln16) * 64 + quad * 16);
            #pragma unroll
            for (int mi = 0; mi < 4; mi++)
                #pragma unroll
                for (int ni = 0; ni < 4; ni++)
                    acc[mi][ni] = __builtin_amdgcn_mfma_f32_16x16x32_bf16(af[mi], bfr[ni],
                                                                          acc[mi][ni], 0, 0, 0);
        }
        __syncthreads();
    }

    // epilogue: region 0=q (sigmoid, token-major), 1=k (tanh+mask, transposed),
    //           2=v (identity, transposed)
    const int region = n0 >> 10;
    const int cbase = n0 & 1023;
    if (region == 0) {
        #pragma unroll
        for (int mi = 0; mi < 4; mi++) {
            #pragma unroll
            for (int r = 0; r < 4; r++) {
                int gm = m0 + wm + mi * 16 + quad * 4 + r;   // C/D row = quad*4+reg
                #pragma unroll
                for (int ni = 0; ni < 4; ni++) {
                    int cc = cbase + wn + ni * 16 + ln16;    // C/D col = lane&15
                    qws[(size_t)gm * D_ + cc] = f2bf(fast_sigmoid(acc[mi][ni][r]));
                }
            }
        }
    } else {
        // phase 1: store tile into LDS transposed [feat][tok], packed 4 toks/write
        #pragma unroll
        for (int mi = 0; mi < 4; mi++) {
            int tok0 = wm + mi * 16 + quad * 4;
            int mk0 = 0, mk1 = 0, mk2 = 0, mk3 = 0;
            if (region == 1) {
                mk0 = mask[m0 + tok0];
                mk1 = mask[m0 + tok0 + 1];
                mk2 = mask[m0 + tok0 + 2];
                mk3 = mask[m0 + tok0 + 3];
            }
            #pragma unroll
            for (int ni = 0; ni < 4; ni++) {
                int fl = wn + ni * 16 + ln16;
                float v0 = acc[mi][ni][0], v1 = acc[mi][ni][1];
                float v2 = acc[mi][ni][2], v3 = acc[mi][ni][3];
                if (region == 1) {
                    v0 = mk0 ? 0.0f : fast_tanh(v0);
                    v1 = mk1 ? 0.0f : fast_tanh(v1);
                    v2 = mk2 ? 0.0f : fast_tanh(v2);
                    v3 = mk3 ? 0.0f : fast_tanh(v3);
                }
                ushort4 pk;
                pk.x = f2bf(v0); pk.y = f2bf(v1); pk.z = f2bf(v2); pk.w = f2bf(v3);
                *(ushort4*)&ShB[fl * CT_STRIDE + tok0] = pk;   // 8B-aligned ds_write_b64
            }
        }
        __syncthreads();
        // phase 2: coalesced transposed global write (256B per feature row)
        unsigned short* dstT = (region == 1) ? kT : vT;
        const int h = cbase >> 7;          // block covers exactly one head
        const int b = m0 >> 13;
        const int ntok0 = m0 & 8191;
        #pragma unroll
        for (int p = 0; p < 8; p++) {
            int fl = p * 16 + (t >> 4);
            int tok = (t & 15) * 8;
            uint4 u = *(const uint4*)&ShB[fl * CT_STRIDE + tok];   // 16B-aligned b128
            *(uint4*)(dstT + ((size_t)(b * 8 + h) * 128 + fl) * 8192 + ntok0 + tok) = u;
        }
    }
}

// ---------------- Kernel 4: kv[bh][d][e] = sum_n kT[d][n]*vT[e][n] (MFMA) -----
// gemm_bt: A = kT (m=d), B^T = vT (n=e). grid (16 K-chunks, 32 bh), tile 128x128,
// BK=32, K-chunk 512. Epilogue: quad-coalesced atomicAdd into fp32 kv.
__global__ __launch_bounds__(256) void kv_mfma(const unsigned short* __restrict__ kT,
                                               const unsigned short* __restrict__ vT,
                                               float* __restrict__ kv) {
    __shared__ unsigned short As[128 * 32];   // kT rows (d)
    __shared__ unsigned short Bs[128 * 32];   // vT rows (e)
    const int t = threadIdx.x;
    const int w = t >> 6, l = t & 63;
    const int quad = l >> 4, ln16 = l & 15;
    const int bh = blockIdx.y;
    const int kc0 = blockIdx.x * 512;
    const int wm = (w >> 1) * 64, wn = (w & 1) * 64;

    f32x4 acc[4][4] = {};

    const size_t base = (size_t)bh * 128 * 8192;
    const unsigned short* aG = kT + base + (size_t)(w * 16 + (l >> 2)) * 8192
                               + (l & 3) * 8 + kc0;
    const unsigned short* bG = vT + base + (size_t)(w * 16 + (l >> 2)) * 8192
                               + (l & 3) * 8 + kc0;
    char* AsB = (char*)As;
    char* BsB = (char*)Bs;
    char* aL0 = AsB + w * 1024;
    char* aL1 = AsB + 4096 + w * 1024;
    char* bL0 = BsB + w * 1024;
    char* bL1 = BsB + 4096 + w * 1024;

    for (int kk = 0; kk < 512; kk += 32) {
        gl_lds16(aG + kk, aL0);
        gl_lds16(aG + 64 * 8192 + kk, aL1);
        gl_lds16(bG + kk, bL0);
        gl_lds16(bG + 64 * 8192 + kk, bL1);
        __syncthreads();
        bf16x8 af[4], bfr[4];
        #pragma unroll
        for (int mi = 0; mi < 4; mi++)
            af[mi] = *(const bf16x8*)(AsB + (wm + mi * 16 + ln16) * 64 + quad * 16);
        #pragma unroll
        for (int ni = 0; ni < 4; ni++)
            bfr[ni] = *(const bf16x8*)(BsB + (wn + ni * 16 + ln16) * 64 + quad * 16);
        #pragma unroll
        for (int mi = 0; mi < 4; mi++)
            #pragma unroll
            for (int ni = 0; ni < 4; ni++)
                acc[mi][ni] = __builtin_amdgcn_mfma_f32_16x16x32_bf16(af[mi], bfr[ni],
                                                                      acc[mi][ni], 0, 0, 0);
        __syncthreads();
    }

    float* dst = kv + (size_t)bh * (HD_ * HD_);
    #pragma unroll
    for (int mi = 0; mi < 4; mi++) {
        #pragma unroll
        for (int r = 0; r < 4; r++) {
            int d = wm + mi * 16 + quad * 4 + r;   // C/D row
            #pragma unroll
            for (int ni = 0; ni < 4; ni++) {
                int e = wn + ni * 16 + ln16;       // C/D col (consecutive lanes)
                atomicAdd(&dst[d * HD_ + e], acc[mi][ni][r]);
            }
        }
    }
}

// ---------------- Kernel 4b: kv fp32 [bh][d][e] -> kvTb bf16 [bh][e][d] -------
__global__ __launch_bounds__(256) void kvcvt(const float* __restrict__ kv,
                                             unsigned short* __restrict__ kvTb) {
    __shared__ float tile[32][132];
    const int bh = blockIdx.x;
    const int c = blockIdx.y;     // d-chunk of 32
    const int t = threadIdx.x;
    // load 32 d-rows x 128 e coalesced
    {
        int r = t >> 3, cc = (t & 7) * 16;
        const float* src = kv + ((size_t)bh * 128 + c * 32 + r) * 128 + cc;
        #pragma unroll
        for (int q4 = 0; q4 < 4; q4++)
            *(float4*)&tile[r][cc + q4 * 4] = *(const float4*)(src + q4 * 4);
    }
    __syncthreads();
    // write transposed: row e, 16 d per thread
    {
        int e = t >> 1, dh = t & 1;
        ushort4 o[4];
        #pragma unroll
        for (int q4 = 0; q4 < 4; q4++) {
            o[q4].x = f2bf(tile[dh * 16 + q4 * 4 + 0][e]);
            o[q4].y = f2bf(tile[dh * 16 + q4 * 4 + 1][e]);
            o[q4].z = f2bf(tile[dh * 16 + q4 * 4 + 2][e]);
            o[q4].w = f2bf(tile[dh * 16 + q4 * 4 + 3][e]);
        }
        unsigned short* dst = kvTb + (size_t)bh * 16384 + e * 128 + c * 32 + dh * 16;
        #pragma unroll
        for (int q4 = 0; q4 < 4; q4++)
            ((ushort4*)dst)[q4] = o[q4];
    }
}

// ---------------- Kernel 5: out[tok][h*128+e] = sum_d q[tok][h*128+d]*kvT[e][d]
// MFMA gemm_bt: A = q slice (row stride D_), B = kvTb[bh] (row stride 128).
// grid (256 m-tiles, 8 heads). K=128, BK=32 -> 4 iters. fp32 output.
__global__ __launch_bounds__(256) void out_mfma(const unsigned short* __restrict__ qws,
                                                const unsigned short* __restrict__ kvTb,
                                                float* __restrict__ out) {
    __shared__ unsigned short As[128 * 32];
    __shared__ unsigned short Bs[128 * 32];
    const int t = threadIdx.x;
    const int w = t >> 6, l = t & 63;
    const int quad = l >> 4, ln16 = l & 15;
    const int m0 = blockIdx.x * 128;
    const int h = blockIdx.y;
    const int b = m0 >> 13;
    const int bh = b * 8 + h;
    const int wm = (w >> 1) * 64, wn = (w & 1) * 64;

    f32x4 acc[4][4] = {};

    const unsigned short* aG = qws + (size_t)(m0 + w * 16 + (l >> 2)) * D_
                               + h * HD_ + (l & 3) * 8;
    const unsigned short* bG = kvTb + (size_t)bh * 16384
                               + (size_t)(w * 16 + (l >> 2)) * 128 + (l & 3) * 8;
    char* AsB = (char*)As;
    char* BsB = (char*)Bs;

    for (int kk = 0; kk < 128; kk += 32) {
        gl_lds16(aG + kk, AsB + w * 1024);
        gl_lds16(aG + 64 * D_ + kk, AsB + 4096 + w * 1024);
        gl_lds16(bG + kk, BsB + w * 1024);
        gl_lds16(bG + 64 * 128 + kk, BsB + 4096 + w * 1024);
        __syncthreads();
        bf16x8 af[4], bfr[4];
        #pragma unroll
        for (int mi = 0; mi < 4; mi++)
            af[mi] = *(const bf16x8*)(AsB + (wm + mi * 16 + ln16) * 64 + quad * 16);
        #pragma unroll
        for (int ni = 0; ni < 4; ni++)
            bfr[ni] = *(const bf16x8*)(BsB + (wn + ni * 16 + ln16) * 64 + quad * 16);
        #pragma unroll
        for (int mi = 0; mi < 4; mi++)
            #pragma unroll
            for (int ni = 0; ni < 4; ni++)
                acc[mi][ni] = __builtin_amdgcn_mfma_f32_16x16x32_bf16(af[mi], bfr[ni],
                                                                      acc[mi][ni], 0, 0, 0);
        __syncthreads();
    }

    #pragma unroll
    for (int mi = 0; mi < 4; mi++) {
        #pragma unroll
        for (int r = 0; r < 4; r++) {
            int gm = m0 + wm + mi * 16 + quad * 4 + r;
            #pragma unroll
            for (int ni = 0; ni < 4; ni++) {
                int e = wn + ni * 16 + ln16;
                out[(size_t)gm * D_ + h * HD_ + e] = acc[mi][ni][r];
            }
        }
    }
}

// ---------------- launch ----------------
extern "C" void kernel_launch(void* const* d_in, const int* in_sizes, int n_in,
                              void* d_out, int out_size, void* d_ws, size_t ws_size,
                              hipStream_t stream) {
    const float* x     = (const float*)d_in[0];
    const int*   mask  = (const int*)d_in[1];
    const float* w     = (const float*)d_in[2];
    const float* gamma = (const float*)d_in[3];
    const float* beta  = (const float*)d_in[4];
    float* out = (float*)d_out;
    char* ws = (char*)d_ws;

    // workspace layout (total ~267 MB)
    unsigned short* xn  = (unsigned short*)(ws + 0);              // 64 MB
    unsigned short* wT  = (unsigned short*)(ws + 67108864ull);    // 6 MB
    unsigned short* qws = (unsigned short*)(ws + 73400320ull);    // 64 MB
    unsigned short* kT  = (unsigned short*)(ws + 140509184ull);   // 64 MB [bh][128][8192]
    unsigned short* vT  = (unsigned short*)(ws + 207618048ull);   // 64 MB [bh][128][8192]
    float* kv           = (float*)(ws + 274726912ull);            // 2 MB fp32 [bh][d][e]
    unsigned short* kvTb = (unsigned short*)(ws + 276824064ull);  // 1 MB bf16 [bh][e][d]

    hipMemsetAsync(kv, 0, 32 * HD_ * HD_ * sizeof(float), stream);
    hipLaunchKernelGGL(ln_kernel, dim3(M_TOT), dim3(256), 0, stream, x, gamma, beta, xn);
    hipLaunchKernelGGL(wt_kernel, dim3(48, 16), dim3(256), 0, stream, w, wT);
    hipLaunchKernelGGL(qkv_gemm, dim3(NQKV / 128, M_TOT / 128), dim3(256), 0, stream,
                       xn, wT, mask, qws, kT, vT);
    hipLaunchKernelGGL(kv_mfma, dim3(16, 32), dim3(256), 0, stream, kT, vT, kv);
    hipLaunchKernelGGL(kvcvt, dim3(32, 4), dim3(256), 0, stream, kv, kvTb);
    hipLaunchKernelGGL(out_mfma, dim3(M_TOT / 128, 8), dim3(256), 0, stream,
                       qws, kvTb, out);
}